// Round 5
// baseline (888.513 us; speedup 1.0000x reference)
//
#include <hip/hip_runtime.h>

#define L_ 2
#define H_ 2048
#define NH_ 16
#define NKV_ 2
#define HD_ 128
#define S_ 1024
#define P_ 1024
#define T_ 2048
#define FF_ 5632
#define QKVN_ 2560   // NH*HD + 2*NKV*HD
#define KOFF_ 2048
#define VOFF_ 2304

#define EPS_ 1e-6f
#define SCALE_ 0.08838834764831845f   // 1/sqrt(128)
#define DEFER_THR_ 8.0f

typedef __bf16 bf16_t;
typedef __bf16 bx8 __attribute__((ext_vector_type(8)));
typedef __bf16 bx4 __attribute__((ext_vector_type(4)));
typedef float  fx4 __attribute__((ext_vector_type(4)));

__device__ __forceinline__ fx4 mfma16(bx8 a, bx8 b, fx4 c) {
  return __builtin_amdgcn_mfma_f32_16x16x32_bf16(a, b, c, 0, 0, 0);
}

// global->LDS direct, 16B per lane; lds dest = wave-uniform base + lane*16
#define GLL16(gsrc, ldst) __builtin_amdgcn_global_load_lds( \
    (__attribute__((address_space(1))) void*)(gsrc),        \
    (__attribute__((address_space(3))) void*)(ldst), 16, 0, 0)

// ---------------- RoPE tables ----------------
__global__ void k_rope_tables(const int* __restrict__ pos, float* __restrict__ ct, float* __restrict__ st) {
  int i = blockIdx.x * 256 + threadIdx.x;
  if (i >= S_ * 64) return;
  int s = i >> 6, d = i & 63;
  float p = (float)pos[s];
  float inv = expf(-(float)(2 * d) * (13.815510557964274f / 128.0f));  // theta=1e6
  float f = p * inv;
  ct[i] = cosf(f);
  st[i] = sinf(f);
}

__global__ void k_copy4(const float* __restrict__ in, float* __restrict__ out, int n4) {
  int i = blockIdx.x * 256 + threadIdx.x;
  if (i < n4) ((fx4*)out)[i] = ((const fx4*)in)[i];
}

// concat bias: [L][2560] = bq | bk | bv
__global__ void k_cbias(const float* __restrict__ bq, const float* __restrict__ bk,
                        const float* __restrict__ bv, float* __restrict__ cb) {
  int i = blockIdx.x * 256 + threadIdx.x;
  if (i >= L_ * QKVN_) return;
  int l = i / QKVN_, j = i % QKVN_;
  float v;
  if (j < KOFF_)      v = bq[l * KOFF_ + j];
  else if (j < VOFF_) v = bk[l * (NKV_ * HD_) + j - KOFF_];
  else                v = bv[l * (NKV_ * HD_) + j - VOFF_];
  cb[i] = v;
}

// ---------------- RMSNorm (one block per row) ----------------
template<int OUTBF>
__global__ __launch_bounds__(256) void k_rmsnorm(const float* __restrict__ x, const float* __restrict__ w,
                                                 void* __restrict__ y) {
  int row = blockIdx.x, tid = threadIdx.x;
  const fx4* xr = (const fx4*)(x + (size_t)row * H_);
  fx4 v0 = xr[tid], v1 = xr[tid + 256];
  float ss = v0[0]*v0[0] + v0[1]*v0[1] + v0[2]*v0[2] + v0[3]*v0[3]
           + v1[0]*v1[0] + v1[1]*v1[1] + v1[2]*v1[2] + v1[3]*v1[3];
  #pragma unroll
  for (int off = 32; off > 0; off >>= 1) ss += __shfl_xor(ss, off);
  __shared__ float red[4];
  if ((tid & 63) == 0) red[tid >> 6] = ss;
  __syncthreads();
  float tot = red[0] + red[1] + red[2] + red[3];
  float rs = rsqrtf(tot * (1.0f / H_) + EPS_);
  const fx4* wr_ = (const fx4*)w;
  fx4 w0 = wr_[tid], w1 = wr_[tid + 256];
  if (OUTBF) {
    bf16_t* yb = (bf16_t*)y + (size_t)row * H_;
    bx4 o0, o1;
    #pragma unroll
    for (int i = 0; i < 4; i++) { o0[i] = (bf16_t)(v0[i] * rs * w0[i]); o1[i] = (bf16_t)(v1[i] * rs * w1[i]); }
    *(bx4*)&yb[tid * 4] = o0;
    *(bx4*)&yb[(tid + 256) * 4] = o1;
  } else {
    float* yf = (float*)y + (size_t)row * H_;
    fx4 o0, o1;
    #pragma unroll
    for (int i = 0; i < 4; i++) { o0[i] = v0[i] * rs * w0[i]; o1[i] = v1[i] * rs * w1[i]; }
    *(fx4*)&yf[tid * 4] = o0;
    *(fx4*)&yf[(tid + 256) * 4] = o1;
  }
}

// ---------------- weight transpose+convert: out[C][R] = bf16(in[R][C]^T) ----------------
__global__ __launch_bounds__(256) void k_transpose_w(const float* __restrict__ in, bf16_t* __restrict__ out,
                                                     int R, int C) {
  __shared__ __attribute__((aligned(16))) float Tt[64 * 68];
  int tid = threadIdx.x;
  int c0 = blockIdx.x * 64, r0 = blockIdx.y * 64;
  #pragma unroll
  for (int j = 0; j < 4; j++) {
    int c = j * 256 + tid;
    int row = c >> 4, col = (c & 15) * 4;
    *(fx4*)&Tt[row * 68 + col] = *(const fx4*)&in[(size_t)(r0 + row) * C + c0 + col];
  }
  __syncthreads();
  #pragma unroll
  for (int j = 0; j < 2; j++) {
    int c = j * 256 + tid;
    int n = c >> 3, ko = (c & 7) * 8;
    bx8 o;
    #pragma unroll
    for (int i = 0; i < 8; i++) o[i] = (bf16_t)Tt[(ko + i) * 68 + n];
    *(bx8*)&out[(size_t)(c0 + n) * R + r0 + ko] = o;
  }
}

// ---------------- GEMM: C[M,N] = A[M,K](bf16) * Bt[N,K]^T (bf16) ----------------
// 128x128 tile, BK=64, 4 waves (each 64x64), 2-phase double-buffered LDS:
// next-tile global_load_lds issued BEFORE compute so ds_read+MFMA hide the
// load latency inside a single block (grids here are ~1 block/CU).
template<int OUTBF, int HASB, int HASR>
__global__ __launch_bounds__(256) void k_gemm(const bf16_t* __restrict__ A, const bf16_t* __restrict__ Bt,
                                              const float* __restrict__ bias, const float* __restrict__ res,
                                              void* __restrict__ out, int M, int N, int K) {
  __shared__ __attribute__((aligned(16))) bf16_t sA[2][128 * 64];
  __shared__ __attribute__((aligned(16))) bf16_t sB[2][128 * 64];
  int tid = threadIdx.x;
  int w = tid >> 6, lane = tid & 63, g = lane >> 4, r = lane & 15;
  int wr = w >> 1, wc = w & 1;
  int m0 = blockIdx.y * 128;
  int n0 = blockIdx.x * 128;
  fx4 acc[4][4] = {};
  int wbase = (tid & ~63) * 16;
  const char* paw = (const char*)&sA[0][0] + (size_t)(wr * 64 + r) * 128;
  const char* pbw = (const char*)&sB[0][0] + (size_t)(wc * 64 + r) * 128;
  int cswz0 = (g * 16) ^ ((r & 7) << 4);
  int cswz1 = (64 + g * 16) ^ ((r & 7) << 4);
  int nk = K >> 6;

  auto STAGE = [&](int buf, int k0) {
    #pragma unroll
    for (int j = 0; j < 4; j++) {
      int d = (j * 256 + tid) * 16;
      int row = d >> 7;
      int inrow = (d & 127) ^ ((row & 7) << 4);
      GLL16((const char*)(A + (size_t)(m0 + row) * K + k0) + inrow,
            (char*)&sA[buf][0] + j * 4096 + wbase);
    }
    #pragma unroll
    for (int j = 0; j < 4; j++) {
      int d = (j * 256 + tid) * 16;
      int row = d >> 7;
      int inrow = (d & 127) ^ ((row & 7) << 4);
      GLL16((const char*)(Bt + (size_t)(n0 + row) * K + k0) + inrow,
            (char*)&sB[buf][0] + j * 4096 + wbase);
    }
  };

  STAGE(0, 0);
  __syncthreads();
  int cur = 0;
  for (int t = 0; t < nk; t++) {
    if (t + 1 < nk) STAGE(cur ^ 1, (t + 1) << 6);   // issue next tile FIRST
    const char* pa = paw + cur * 16384;
    const char* pb = pbw + cur * 16384;
    bx8 fa[4][2], fb[4][2];
    #pragma unroll
    for (int m = 0; m < 4; m++) {
      fa[m][0] = *(const bx8*)(pa + m * 2048 + cswz0);
      fa[m][1] = *(const bx8*)(pa + m * 2048 + cswz1);
    }
    #pragma unroll
    for (int n = 0; n < 4; n++) {
      fb[n][0] = *(const bx8*)(pb + n * 2048 + cswz0);
      fb[n][1] = *(const bx8*)(pb + n * 2048 + cswz1);
    }
    #pragma unroll
    for (int kk = 0; kk < 2; kk++)
      #pragma unroll
      for (int m = 0; m < 4; m++)
        #pragma unroll
        for (int n = 0; n < 4; n++)
          acc[m][n] = mfma16(fa[m][kk], fb[n][kk], acc[m][n]);
    __syncthreads();   // drains vmcnt (next tile staged) + lgkm; guards buf reuse
    cur ^= 1;
  }
  #pragma unroll
  for (int m = 0; m < 4; m++)
    #pragma unroll
    for (int n = 0; n < 4; n++) {
      int col = n0 + wc * 64 + n * 16 + r;
      #pragma unroll
      for (int rr = 0; rr < 4; rr++) {
        int row = m0 + wr * 64 + m * 16 + 4 * g + rr;
        float v = acc[m][n][rr];
        if (HASB) v += bias[col];
        if (HASR) v += res[(size_t)row * N + col];
        if (OUTBF) ((bf16_t*)out)[(size_t)row * N + col] = (bf16_t)v;
        else       ((float*)out)[(size_t)row * N + col] = v;
      }
    }
}

// ---------------- RoPE on Q: qkv[S][2560] bf16 -> [NH][S][HD] bf16 ----------------
__global__ void k_rope_q(const bf16_t* __restrict__ qkv, const float* __restrict__ ct,
                         const float* __restrict__ st, bf16_t* __restrict__ qout) {
  int i = blockIdx.x * 256 + threadIdx.x;
  if (i >= S_ * NH_ * 64) return;
  int d = i & 63, h = (i >> 6) & 15, s = i >> 10;
  size_t ib = (size_t)s * QKVN_ + h * HD_;
  float x1 = (float)qkv[ib + d];
  float x2 = (float)qkv[ib + d + 64];
  float c = ct[s * 64 + d], sn = st[s * 64 + d];
  size_t ob = ((size_t)h * S_ + s) * HD_;
  qout[ob + d]      = (bf16_t)(x1 * c - x2 * sn);
  qout[ob + d + 64] = (bf16_t)(x2 * c + x1 * sn);
}

// ---------------- K: rope new keys + concat past -> bf16 [NKV][T][HD] + f32 present ----------------
__global__ void k_build_k(const bf16_t* __restrict__ qkv, const float* __restrict__ pastk,
                          const float* __restrict__ ct, const float* __restrict__ st,
                          bf16_t* __restrict__ kc, float* __restrict__ pk_out) {
  int i = blockIdx.x * 256 + threadIdx.x;
  if (i >= NKV_ * T_ * 64) return;
  int d = i & 63, t = (i >> 6) & (T_ - 1), kv = i >> 17;
  size_t cb = ((size_t)kv * T_ + t) * HD_;
  if (t < P_) {
    size_t pb = ((size_t)kv * P_ + t) * HD_;
    float a = pastk[pb + d], b = pastk[pb + d + 64];
    kc[cb + d] = (bf16_t)a; kc[cb + d + 64] = (bf16_t)b;
    pk_out[cb + d] = a;     pk_out[cb + d + 64] = b;
  } else {
    int s = t - P_;
    size_t ib = (size_t)s * QKVN_ + KOFF_ + kv * HD_;
    float x1 = (float)qkv[ib + d];
    float x2 = (float)qkv[ib + d + 64];
    float c = ct[s * 64 + d], sn = st[s * 64 + d];
    float k1 = x1 * c - x2 * sn, k2 = x2 * c + x1 * sn;
    kc[cb + d] = (bf16_t)k1; kc[cb + d + 64] = (bf16_t)k2;
    pk_out[cb + d] = k1;     pk_out[cb + d + 64] = k2;
  }
}

// ---------------- V: concat past+new -> VT bf16 [NKV][HD][T] + f32 present ----------------
__global__ __launch_bounds__(256) void k_build_vt(const bf16_t* __restrict__ qkv, const float* __restrict__ pastv,
                                                  bf16_t* __restrict__ vt, float* __restrict__ pv_out) {
  int t0 = blockIdx.x * 64, d0 = blockIdx.y * 64, kv = blockIdx.z;
  __shared__ __attribute__((aligned(16))) float Tt[64 * 68];
  int tid = threadIdx.x;
  if (t0 < P_) {
    #pragma unroll
    for (int j = 0; j < 4; j++) {
      int c = j * 256 + tid;
      int row = c >> 4, col = (c & 15) * 4;
      int t = t0 + row;
      fx4 v = *(const fx4*)&pastv[((size_t)kv * P_ + t) * HD_ + d0 + col];
      *(fx4*)&Tt[row * 68 + col] = v;
      *(fx4*)&pv_out[((size_t)kv * T_ + t) * HD_ + d0 + col] = v;
    }
  } else {
    #pragma unroll
    for (int j = 0; j < 4; j++) {
      int c = j * 256 + tid;
      int row = c >> 4, col = (c & 15) * 4;
      int t = t0 + row;
      bx4 b = *(const bx4*)&qkv[(size_t)(t - P_) * QKVN_ + VOFF_ + kv * HD_ + d0 + col];
      fx4 v;
      #pragma unroll
      for (int q = 0; q < 4; q++) v[q] = (float)b[q];
      *(fx4*)&Tt[row * 68 + col] = v;
      *(fx4*)&pv_out[((size_t)kv * T_ + t) * HD_ + d0 + col] = v;
    }
  }
  __syncthreads();
  #pragma unroll
  for (int j = 0; j < 2; j++) {
    int c = j * 256 + tid;
    int n = c >> 3, ko = (c & 7) * 8;
    bx8 o;
    #pragma unroll
    for (int i = 0; i < 8; i++) o[i] = (bf16_t)Tt[(ko + i) * 68 + n];
    *(bx8*)&vt[((size_t)kv * HD_ + d0 + n) * T_ + t0 + ko] = o;
  }
}

// ---------------- flash attention, T-split across 4 waves + LDS merge ----------------
__global__ __launch_bounds__(256) void k_attn(const bf16_t* __restrict__ Q, const bf16_t* __restrict__ Kc,
                                              const bf16_t* __restrict__ VT, bf16_t* __restrict__ O) {
  int tid = threadIdx.x;
  int w = tid >> 6, lane = tid & 63, g = lane >> 4, r = lane & 15;
  int h = blockIdx.y, kv = h >> 3;
  int m0 = ((int)gridDim.x - 1 - (int)blockIdx.x) * 16;   // heavy blocks first
  __shared__ __attribute__((aligned(16))) bf16_t Plds[4][16][40];
  __shared__ float Om[4][16][132];
  __shared__ float Ml[4][16], Ll[4][16];
  const bf16_t* qb = Q + ((size_t)h * S_ + m0 + r) * HD_ + g * 8;
  bx8 qf[4];
  #pragma unroll
  for (int kc = 0; kc < 4; kc++) qf[kc] = *(const bx8*)(qb + kc * 32);
  fx4 of[8] = {};
  float mrun[4], lrun[4];
  #pragma unroll
  for (int i = 0; i < 4; i++) { mrun[i] = -1e30f; lrun[i] = 0.0f; }
  int ntile = (P_ + m0 + 16 + 31) >> 5;
  const bf16_t* kb0 = Kc + (size_t)kv * T_ * HD_ + g * 8;
  const bf16_t* vb0 = VT + (size_t)kv * HD_ * T_ + g * 8;
  int lim = P_ + m0 + 4 * g;
  bx8 kcur[2][4], vcur[8];
  {
    int t0 = w * 32;
    #pragma unroll
    for (int nt = 0; nt < 2; nt++)
      #pragma unroll
      for (int kc = 0; kc < 4; kc++)
        kcur[nt][kc] = *(const bx8*)(kb0 + (size_t)(t0 + nt * 16 + r) * HD_ + kc * 32);
    #pragma unroll
    for (int dt = 0; dt < 8; dt++)
      vcur[dt] = *(const bx8*)(vb0 + (size_t)(dt * 16 + r) * T_ + t0);
  }
  for (int it = w; it < ntile; it += 4) {
    int t0 = it * 32;
    fx4 sc[2] = {};
    #pragma unroll
    for (int nt = 0; nt < 2; nt++)
      #pragma unroll
      for (int kc = 0; kc < 4; kc++)
        sc[nt] = mfma16(qf[kc], kcur[nt][kc], sc[nt]);
    int tn = (it + 4 < ntile) ? (t0 + 128) : t0;
    bx8 knx[2][4], vnx[8];
    #pragma unroll
    for (int nt = 0; nt < 2; nt++)
      #pragma unroll
      for (int kc = 0; kc < 4; kc++)
        knx[nt][kc] = *(const bx8*)(kb0 + (size_t)(tn + nt * 16 + r) * HD_ + kc * 32);
    #pragma unroll
    for (int dt = 0; dt < 8; dt++)
      vnx[dt] = *(const bx8*)(vb0 + (size_t)(dt * 16 + r) * T_ + tn);
    float lm[4], pr0[4], pr1[4];
    #pragma unroll
    for (int rr = 0; rr < 4; rr++) {
      #pragma unroll
      for (int nt = 0; nt < 2; nt++) {
        int key = t0 + nt * 16 + r;
        float sv = sc[nt][rr] * SCALE_;
        sc[nt][rr] = (key > lim + rr) ? -1e30f : sv;
      }
      lm[rr] = fmaxf(sc[0][rr], sc[1][rr]);
    }
    int ok = (lm[0] <= mrun[0] + DEFER_THR_) & (lm[1] <= mrun[1] + DEFER_THR_) &
             (lm[2] <= mrun[2] + DEFER_THR_) & (lm[3] <= mrun[3] + DEFER_THR_);
    if (!__all(ok)) {
      float tm[4], av[4];
      #pragma unroll
      for (int rr = 0; rr < 4; rr++) tm[rr] = lm[rr];
      #pragma unroll
      for (int off = 1; off < 16; off <<= 1)
        #pragma unroll
        for (int rr = 0; rr < 4; rr++) tm[rr] = fmaxf(tm[rr], __shfl_xor(tm[rr], off));
      #pragma unroll
      for (int rr = 0; rr < 4; rr++) {
        float mn = fmaxf(mrun[rr], tm[rr]);
        av[rr] = __expf(mrun[rr] - mn);
        mrun[rr] = mn;
        lrun[rr] *= av[rr];
      }
      #pragma unroll
      for (int f = 0; f < 8; f++)
        #pragma unroll
        for (int rr = 0; rr < 4; rr++) of[f][rr] *= av[rr];
    }
    #pragma unroll
    for (int rr = 0; rr < 4; rr++) {
      pr0[rr] = __expf(sc[0][rr] - mrun[rr]);
      pr1[rr] = __expf(sc[1][rr] - mrun[rr]);
      lrun[rr] += pr0[rr] + pr1[rr];
    }
    #pragma unroll
    for (int rr = 0; rr < 4; rr++) {
      Plds[w][4 * g + rr][r]      = (bf16_t)pr0[rr];
      Plds[w][4 * g + rr][16 + r] = (bf16_t)pr1[rr];
    }
    asm volatile("s_waitcnt lgkmcnt(0)" ::: "memory");
    __builtin_amdgcn_sched_barrier(0);
    bx8 pa = *(const bx8*)&Plds[w][r][g * 8];
    #pragma unroll
    for (int dt = 0; dt < 8; dt++)
      of[dt] = mfma16(pa, vcur[dt], of[dt]);
    #pragma unroll
    for (int nt = 0; nt < 2; nt++)
      #pragma unroll
      for (int kc = 0; kc < 4; kc++)
        kcur[nt][kc] = knx[nt][kc];
    #pragma unroll
    for (int dt = 0; dt < 8; dt++) vcur[dt] = vnx[dt];
  }
  #pragma unroll
  for (int off = 1; off < 16; off <<= 1)
    #pragma unroll
    for (int rr = 0; rr < 4; rr++) lrun[rr] += __shfl_xor(lrun[rr], off);
  #pragma unroll
  for (int rr = 0; rr < 4; rr++) {
    Ml[w][4 * g + rr] = mrun[rr];
    Ll[w][4 * g + rr] = lrun[rr];
  }
  #pragma unroll
  for (int dt = 0; dt < 8; dt++)
    #pragma unroll
    for (int rr = 0; rr < 4; rr++)
      Om[w][4 * g + rr][dt * 16 + r] = of[dt][rr];
  __syncthreads();
  int row = tid >> 4, c0 = (tid & 15) * 8;
  float gm = fmaxf(fmaxf(Ml[0][row], Ml[1][row]), fmaxf(Ml[2][row], Ml[3][row]));
  float l = 0.0f;
  float oacc[8] = {};
  #pragma unroll
  for (int ww = 0; ww < 4; ww++) {
    float scl = __expf(Ml[ww][row] - gm);
    l += Ll[ww][row] * scl;
    #pragma unroll
    for (int j = 0; j < 8; j++) oacc[j] += Om[ww][row][c0 + j] * scl;
  }
  float inv = 1.0f / l;
  #pragma unroll
  for (int j = 0; j < 8; j++)
    O[(size_t)(m0 + row) * H_ + h * HD_ + c0 + j] = (bf16_t)(oacc[j] * inv);
}

// ---------------- silu(gate)*up ----------------
__global__ void k_silu_mul(const bf16_t* __restrict__ gb, const bf16_t* __restrict__ ub,
                           bf16_t* __restrict__ ob, int n8) {
  int i = blockIdx.x * 256 + threadIdx.x;
  if (i >= n8) return;
  bx8 gv = ((const bx8*)gb)[i], uv = ((const bx8*)ub)[i];
  bx8 ov;
  #pragma unroll
  for (int j = 0; j < 8; j++) {
    float x = (float)gv[j], y = (float)uv[j];
    float s = x / (1.0f + __expf(-x));
    ov[j] = (bf16_t)(s * y);
  }
  ((bx8*)ob)[i] = ov;
}

// ---------------- host-side launch ----------------
extern "C" void kernel_launch(void* const* d_in, const int* in_sizes, int n_in,
                              void* d_out, int out_size, void* d_ws, size_t ws_size,
                              hipStream_t stream) {
  const float* embeds = (const float*)d_in[0];
  const int*   pos    = (const int*)d_in[1];
  const float* past_k = (const float*)d_in[2];
  const float* past_v = (const float*)d_in[3];
  const float* ln1    = (const float*)d_in[4];
  const float* wq     = (const float*)d_in[5];
  const float* bq     = (const float*)d_in[6];
  const float* wk     = (const float*)d_in[7];
  const float* bk     = (const float*)d_in[8];
  const float* wv     = (const float*)d_in[9];
  const float* bv     = (const float*)d_in[10];
  const float* wo     = (const float*)d_in[11];
  const float* ln2    = (const float*)d_in[12];
  const float* wg     = (const float*)d_in[13];
  const float* wu     = (const float*)d_in[14];
  const float* wd     = (const float*)d_in[15];
  const float* normw  = (const float*)d_in[16];

  char* wsp = (char*)d_ws;
  auto take = [&](size_t n) { char* p = wsp; wsp += (n + 255) & ~(size_t)255; return (void*)p; };
  float*  cos_t  = (float*)take((size_t)S_ * 64 * 4);
  float*  sin_t  = (float*)take((size_t)S_ * 64 * 4);
  float*  cbias  = (float*)take((size_t)L_ * QKVN_ * 4);
  float*  hidden = (float*)take((size_t)S_ * H_ * 4);
  bf16_t* hnorm  = (bf16_t*)take((size_t)S_ * H_ * 2);
  bf16_t* qkv    = (bf16_t*)take((size_t)S_ * QKVN_ * 2);
  bf16_t* qrope  = (bf16_t*)take((size_t)NH_ * S_ * HD_ * 2);
  bf16_t* kcache = (bf16_t*)take((size_t)NKV_ * T_ * HD_ * 2);
  bf16_t* vtr    = (bf16_t*)take((size_t)NKV_ * HD_ * T_ * 2);
  bf16_t* attno  = (bf16_t*)take((size_t)S_ * H_ * 2);
  bf16_t* gateb  = (bf16_t*)take((size_t)S_ * FF_ * 2);
  bf16_t* upb    = (bf16_t*)take((size_t)S_ * FF_ * 2);
  bf16_t* hgb    = (bf16_t*)take((size_t)S_ * FF_ * 2);
  bf16_t* wT     = (bf16_t*)take((size_t)FF_ * H_ * 2);   // max: 5632x2048 bf16

  float* out_h = (float*)d_out;

  k_rope_tables<<<256, 256, 0, stream>>>(pos, cos_t, sin_t);
  k_cbias<<<(L_ * QKVN_ + 255) / 256, 256, 0, stream>>>(bq, bk, bv, cbias);
  k_copy4<<<(S_ * H_ / 4 + 255) / 256, 256, 0, stream>>>(embeds, hidden, S_ * H_ / 4);

  for (int l = 0; l < L_; l++) {
    const float* wq_l = wq + (size_t)l * H_ * (NH_ * HD_);
    const float* wk_l = wk + (size_t)l * H_ * (NKV_ * HD_);
    const float* wv_l = wv + (size_t)l * H_ * (NKV_ * HD_);
    const float* wo_l = wo + (size_t)l * (NH_ * HD_) * H_;
    const float* wg_l = wg + (size_t)l * H_ * FF_;
    const float* wu_l = wu + (size_t)l * H_ * FF_;
    const float* wd_l = wd + (size_t)l * FF_ * H_;
    const float* pk_in = past_k + (size_t)l * NKV_ * P_ * HD_;
    const float* pv_in = past_v + (size_t)l * NKV_ * P_ * HD_;
    float* pk_out = out_h + (size_t)S_ * H_ + (size_t)l * 2 * NKV_ * T_ * HD_;
    float* pv_out = pk_out + (size_t)NKV_ * T_ * HD_;

    // attn input norm
    k_rmsnorm<1><<<S_, 256, 0, stream>>>(hidden, ln1 + (size_t)l * H_, hnorm);
    // fused QKV projection: Bt = [wq^T | wk^T | wv^T] as [2560][2048]
    k_transpose_w<<<dim3(32, 32), 256, 0, stream>>>(wq_l, wT, H_, NH_ * HD_);
    k_transpose_w<<<dim3(4, 32), 256, 0, stream>>>(wk_l, wT + (size_t)KOFF_ * H_, H_, NKV_ * HD_);
    k_transpose_w<<<dim3(4, 32), 256, 0, stream>>>(wv_l, wT + (size_t)VOFF_ * H_, H_, NKV_ * HD_);
    k_gemm<1, 1, 0><<<dim3(QKVN_ / 128, S_ / 128), 256, 0, stream>>>(
        hnorm, wT, cbias + (size_t)l * QKVN_, nullptr, qkv, S_, QKVN_, H_);
    // rope + cache build (also writes f32 present outputs)
    k_rope_q<<<(S_ * NH_ * 64) / 256, 256, 0, stream>>>(qkv, cos_t, sin_t, qrope);
    k_build_k<<<(NKV_ * T_ * 64) / 256, 256, 0, stream>>>(qkv, pk_in, cos_t, sin_t, kcache, pk_out);
    k_build_vt<<<dim3(T_ / 64, HD_ / 64, NKV_), 256, 0, stream>>>(qkv, pv_in, vtr, pv_out);
    // attention
    k_attn<<<dim3(S_ / 16, NH_), 256, 0, stream>>>(qrope, kcache, vtr, attno);
    // output projection + residual
    k_transpose_w<<<dim3(32, 32), 256, 0, stream>>>(wo_l, wT, NH_ * HD_, H_);
    k_gemm<0, 0, 1><<<dim3(H_ / 128, S_ / 128), 256, 0, stream>>>(
        attno, wT, nullptr, hidden, hidden, S_, H_, NH_ * HD_);
    // MLP
    k_rmsnorm<1><<<S_, 256, 0, stream>>>(hidden, ln2 + (size_t)l * H_, hnorm);
    k_transpose_w<<<dim3(88, 32), 256, 0, stream>>>(wg_l, wT, H_, FF_);
    k_gemm<1, 0, 0><<<dim3(FF_ / 128, S_ / 128), 256, 0, stream>>>(
        hnorm, wT, nullptr, nullptr, gateb, S_, FF_, H_);
    k_transpose_w<<<dim3(88, 32), 256, 0, stream>>>(wu_l, wT, H_, FF_);
    k_gemm<1, 0, 0><<<dim3(FF_ / 128, S_ / 128), 256, 0, stream>>>(
        hnorm, wT, nullptr, nullptr, upb, S_, FF_, H_);
    k_silu_mul<<<(S_ * FF_ / 8) / 256, 256, 0, stream>>>(gateb, upb, hgb, S_ * FF_ / 8);
    k_transpose_w<<<dim3(32, 88), 256, 0, stream>>>(wd_l, wT, FF_, H_);
    k_gemm<0, 0, 1><<<dim3(H_ / 128, S_ / 128), 256, 0, stream>>>(
        hgb, wT, nullptr, hidden, hidden, S_, H_, FF_);
  }
  k_rmsnorm<0><<<S_, 256, 0, stream>>>(hidden, normw, out_h);
}

// Round 6
// 705.736 us; speedup vs baseline: 1.2590x; 1.2590x over previous
//
#include <hip/hip_runtime.h>

#define L_ 2
#define H_ 2048
#define NH_ 16
#define NKV_ 2
#define HD_ 128
#define S_ 1024
#define P_ 1024
#define T_ 2048
#define FF_ 5632
#define QKVN_ 2560   // NH*HD + 2*NKV*HD
#define KOFF_ 2048
#define VOFF_ 2304

#define EPS_ 1e-6f
#define SCALE_ 0.08838834764831845f   // 1/sqrt(128)
#define DEFER_THR_ 8.0f

typedef __bf16 bf16_t;
typedef __bf16 bx8 __attribute__((ext_vector_type(8)));
typedef __bf16 bx4 __attribute__((ext_vector_type(4)));
typedef float  fx4 __attribute__((ext_vector_type(4)));

__device__ __forceinline__ fx4 mfma16(bx8 a, bx8 b, fx4 c) {
  return __builtin_amdgcn_mfma_f32_16x16x32_bf16(a, b, c, 0, 0, 0);
}

// global->LDS direct, 16B per lane; lds dest = wave-uniform base + lane*16
#define GLL16(gsrc, ldst) __builtin_amdgcn_global_load_lds( \
    (__attribute__((address_space(1))) void*)(gsrc),        \
    (__attribute__((address_space(3))) void*)(ldst), 16, 0, 0)

// ---------------- RoPE tables ----------------
__global__ void k_rope_tables(const int* __restrict__ pos, float* __restrict__ ct, float* __restrict__ st) {
  int i = blockIdx.x * 256 + threadIdx.x;
  if (i >= S_ * 64) return;
  int s = i >> 6, d = i & 63;
  float p = (float)pos[s];
  float inv = expf(-(float)(2 * d) * (13.815510557964274f / 128.0f));  // theta=1e6
  float f = p * inv;
  ct[i] = cosf(f);
  st[i] = sinf(f);
}

__global__ void k_copy4(const float* __restrict__ in, float* __restrict__ out, int n4) {
  int i = blockIdx.x * 256 + threadIdx.x;
  if (i < n4) ((fx4*)out)[i] = ((const fx4*)in)[i];
}

// concat bias: [L][2560] = bq | bk | bv
__global__ void k_cbias(const float* __restrict__ bq, const float* __restrict__ bk,
                        const float* __restrict__ bv, float* __restrict__ cb) {
  int i = blockIdx.x * 256 + threadIdx.x;
  if (i >= L_ * QKVN_) return;
  int l = i / QKVN_, j = i % QKVN_;
  float v;
  if (j < KOFF_)      v = bq[l * KOFF_ + j];
  else if (j < VOFF_) v = bk[l * (NKV_ * HD_) + j - KOFF_];
  else                v = bv[l * (NKV_ * HD_) + j - VOFF_];
  cb[i] = v;
}

// ---------------- RMSNorm (one block per row) ----------------
template<int OUTBF>
__global__ __launch_bounds__(256) void k_rmsnorm(const float* __restrict__ x, const float* __restrict__ w,
                                                 void* __restrict__ y) {
  int row = blockIdx.x, tid = threadIdx.x;
  const fx4* xr = (const fx4*)(x + (size_t)row * H_);
  fx4 v0 = xr[tid], v1 = xr[tid + 256];
  float ss = v0[0]*v0[0] + v0[1]*v0[1] + v0[2]*v0[2] + v0[3]*v0[3]
           + v1[0]*v1[0] + v1[1]*v1[1] + v1[2]*v1[2] + v1[3]*v1[3];
  #pragma unroll
  for (int off = 32; off > 0; off >>= 1) ss += __shfl_xor(ss, off);
  __shared__ float red[4];
  if ((tid & 63) == 0) red[tid >> 6] = ss;
  __syncthreads();
  float tot = red[0] + red[1] + red[2] + red[3];
  float rs = rsqrtf(tot * (1.0f / H_) + EPS_);
  const fx4* wr_ = (const fx4*)w;
  fx4 w0 = wr_[tid], w1 = wr_[tid + 256];
  if (OUTBF) {
    bf16_t* yb = (bf16_t*)y + (size_t)row * H_;
    bx4 o0, o1;
    #pragma unroll
    for (int i = 0; i < 4; i++) { o0[i] = (bf16_t)(v0[i] * rs * w0[i]); o1[i] = (bf16_t)(v1[i] * rs * w1[i]); }
    *(bx4*)&yb[tid * 4] = o0;
    *(bx4*)&yb[(tid + 256) * 4] = o1;
  } else {
    float* yf = (float*)y + (size_t)row * H_;
    fx4 o0, o1;
    #pragma unroll
    for (int i = 0; i < 4; i++) { o0[i] = v0[i] * rs * w0[i]; o1[i] = v1[i] * rs * w1[i]; }
    *(fx4*)&yf[tid * 4] = o0;
    *(fx4*)&yf[(tid + 256) * 4] = o1;
  }
}

// ---------------- weight transpose+convert: out[C][R] = bf16(in[R][C]^T) ----------------
__global__ __launch_bounds__(256) void k_transpose_w(const float* __restrict__ in, bf16_t* __restrict__ out,
                                                     int R, int C) {
  __shared__ __attribute__((aligned(16))) float Tt[64 * 68];
  int tid = threadIdx.x;
  int c0 = blockIdx.x * 64, r0 = blockIdx.y * 64;
  #pragma unroll
  for (int j = 0; j < 4; j++) {
    int c = j * 256 + tid;
    int row = c >> 4, col = (c & 15) * 4;
    *(fx4*)&Tt[row * 68 + col] = *(const fx4*)&in[(size_t)(r0 + row) * C + c0 + col];
  }
  __syncthreads();
  #pragma unroll
  for (int j = 0; j < 2; j++) {
    int c = j * 256 + tid;
    int n = c >> 3, ko = (c & 7) * 8;
    bx8 o;
    #pragma unroll
    for (int i = 0; i < 8; i++) o[i] = (bf16_t)Tt[(ko + i) * 68 + n];
    *(bx8*)&out[(size_t)(c0 + n) * R + r0 + ko] = o;
  }
}

// ---------------- GEMM: C[M,N] = A[M,K](bf16) * Bt[N,K]^T (bf16) ----------------
// m97 structure: BM=64 BN=128 BK=64, global_load_lds(16B) staging, XOR-swizzled LDS.
template<int OUTBF, int HASB, int HASR>
__global__ __launch_bounds__(256) void k_gemm(const bf16_t* __restrict__ A, const bf16_t* __restrict__ Bt,
                                              const float* __restrict__ bias, const float* __restrict__ res,
                                              void* __restrict__ out, int M, int N, int K) {
  __shared__ __attribute__((aligned(16))) bf16_t sA[64 * 64];
  __shared__ __attribute__((aligned(16))) bf16_t sB[128 * 64];
  int tid = threadIdx.x;
  int w = tid >> 6, lane = tid & 63, g = lane >> 4, r = lane & 15;
  int wr = w >> 1, wc = w & 1;
  int m0 = blockIdx.y * 64;
  int n0 = blockIdx.x * 128;
  fx4 acc[2][4] = {};
  int swz = (r & 7) << 4;
  const char* pa = (const char*)sA + (wr * 32 + r) * 128;
  const char* pb = (const char*)sB + (wc * 64 + r) * 128;
  int col0 = (g * 16) ^ swz;
  int col1 = (64 + g * 16) ^ swz;
  int wbase = (tid & ~63) * 16;

  for (int k0 = 0; k0 < K; k0 += 64) {
    #pragma unroll
    for (int j = 0; j < 2; j++) {
      int d = (j * 256 + tid) * 16;
      int row = d >> 7;
      int inrow = (d & 127) ^ ((row & 7) << 4);
      const char* src = (const char*)(A + (size_t)(m0 + row) * K + k0) + inrow;
      GLL16(src, (char*)sA + j * 4096 + wbase);
    }
    #pragma unroll
    for (int j = 0; j < 4; j++) {
      int d = (j * 256 + tid) * 16;
      int row = d >> 7;
      int inrow = (d & 127) ^ ((row & 7) << 4);
      const char* src = (const char*)(Bt + (size_t)(n0 + row) * K + k0) + inrow;
      GLL16(src, (char*)sB + j * 4096 + wbase);
    }
    __syncthreads();
    bx8 fa[2][2], fb[4][2];
    #pragma unroll
    for (int m = 0; m < 2; m++) {
      fa[m][0] = *(const bx8*)(pa + m * 2048 + col0);
      fa[m][1] = *(const bx8*)(pa + m * 2048 + col1);
    }
    #pragma unroll
    for (int n = 0; n < 4; n++) {
      fb[n][0] = *(const bx8*)(pb + n * 2048 + col0);
      fb[n][1] = *(const bx8*)(pb + n * 2048 + col1);
    }
    #pragma unroll
    for (int kk = 0; kk < 2; kk++)
      #pragma unroll
      for (int n = 0; n < 4; n++) {
        acc[0][n] = mfma16(fa[0][kk], fb[n][kk], acc[0][n]);
        acc[1][n] = mfma16(fa[1][kk], fb[n][kk], acc[1][n]);
      }
    __syncthreads();
  }
  #pragma unroll
  for (int m = 0; m < 2; m++)
    #pragma unroll
    for (int n = 0; n < 4; n++) {
      int col = n0 + wc * 64 + n * 16 + r;
      #pragma unroll
      for (int rr = 0; rr < 4; rr++) {
        int row = m0 + wr * 32 + m * 16 + 4 * g + rr;
        float v = acc[m][n][rr];
        if (HASB) v += bias[col];
        if (HASR) v += res[(size_t)row * N + col];
        if (OUTBF) ((bf16_t*)out)[(size_t)row * N + col] = (bf16_t)v;
        else       ((float*)out)[(size_t)row * N + col] = v;
      }
    }
}

// ---------------- RoPE on Q: qkv[S][2560] bf16 -> [NH][S][HD] bf16 ----------------
__global__ void k_rope_q(const bf16_t* __restrict__ qkv, const float* __restrict__ ct,
                         const float* __restrict__ st, bf16_t* __restrict__ qout) {
  int i = blockIdx.x * 256 + threadIdx.x;
  if (i >= S_ * NH_ * 64) return;
  int d = i & 63, h = (i >> 6) & 15, s = i >> 10;
  size_t ib = (size_t)s * QKVN_ + h * HD_;
  float x1 = (float)qkv[ib + d];
  float x2 = (float)qkv[ib + d + 64];
  float c = ct[s * 64 + d], sn = st[s * 64 + d];
  size_t ob = ((size_t)h * S_ + s) * HD_;
  qout[ob + d]      = (bf16_t)(x1 * c - x2 * sn);
  qout[ob + d + 64] = (bf16_t)(x2 * c + x1 * sn);
}

// ---------------- K: rope new keys + concat past -> bf16 [NKV][T][HD] + f32 present ----------------
__global__ void k_build_k(const bf16_t* __restrict__ qkv, const float* __restrict__ pastk,
                          const float* __restrict__ ct, const float* __restrict__ st,
                          bf16_t* __restrict__ kc, float* __restrict__ pk_out) {
  int i = blockIdx.x * 256 + threadIdx.x;
  if (i >= NKV_ * T_ * 64) return;
  int d = i & 63, t = (i >> 6) & (T_ - 1), kv = i >> 17;
  size_t cb = ((size_t)kv * T_ + t) * HD_;
  if (t < P_) {
    size_t pb = ((size_t)kv * P_ + t) * HD_;
    float a = pastk[pb + d], b = pastk[pb + d + 64];
    kc[cb + d] = (bf16_t)a; kc[cb + d + 64] = (bf16_t)b;
    pk_out[cb + d] = a;     pk_out[cb + d + 64] = b;
  } else {
    int s = t - P_;
    size_t ib = (size_t)s * QKVN_ + KOFF_ + kv * HD_;
    float x1 = (float)qkv[ib + d];
    float x2 = (float)qkv[ib + d + 64];
    float c = ct[s * 64 + d], sn = st[s * 64 + d];
    float k1 = x1 * c - x2 * sn, k2 = x2 * c + x1 * sn;
    kc[cb + d] = (bf16_t)k1; kc[cb + d + 64] = (bf16_t)k2;
    pk_out[cb + d] = k1;     pk_out[cb + d + 64] = k2;
  }
}

// ---------------- V: concat past+new -> VT bf16 [NKV][HD][T] + f32 present ----------------
__global__ __launch_bounds__(256) void k_build_vt(const bf16_t* __restrict__ qkv, const float* __restrict__ pastv,
                                                  bf16_t* __restrict__ vt, float* __restrict__ pv_out) {
  int t0 = blockIdx.x * 64, d0 = blockIdx.y * 64, kv = blockIdx.z;
  __shared__ __attribute__((aligned(16))) float Tt[64 * 68];
  int tid = threadIdx.x;
  if (t0 < P_) {
    #pragma unroll
    for (int j = 0; j < 4; j++) {
      int c = j * 256 + tid;
      int row = c >> 4, col = (c & 15) * 4;
      int t = t0 + row;
      fx4 v = *(const fx4*)&pastv[((size_t)kv * P_ + t) * HD_ + d0 + col];
      *(fx4*)&Tt[row * 68 + col] = v;
      *(fx4*)&pv_out[((size_t)kv * T_ + t) * HD_ + d0 + col] = v;
    }
  } else {
    #pragma unroll
    for (int j = 0; j < 4; j++) {
      int c = j * 256 + tid;
      int row = c >> 4, col = (c & 15) * 4;
      int t = t0 + row;
      bx4 b = *(const bx4*)&qkv[(size_t)(t - P_) * QKVN_ + VOFF_ + kv * HD_ + d0 + col];
      fx4 v;
      #pragma unroll
      for (int q = 0; q < 4; q++) v[q] = (float)b[q];
      *(fx4*)&Tt[row * 68 + col] = v;
      *(fx4*)&pv_out[((size_t)kv * T_ + t) * HD_ + d0 + col] = v;
    }
  }
  __syncthreads();
  #pragma unroll
  for (int j = 0; j < 2; j++) {
    int c = j * 256 + tid;
    int n = c >> 3, ko = (c & 7) * 8;
    bx8 o;
    #pragma unroll
    for (int i = 0; i < 8; i++) o[i] = (bf16_t)Tt[(ko + i) * 68 + n];
    *(bx8*)&vt[((size_t)kv * HD_ + d0 + n) * T_ + t0 + ko] = o;
  }
}

// ---------------- flash attention v5: block = 64 q-rows, LDS-staged K/V tiles ----------------
// 2-phase double-buffered: stage(next) issued BEFORE compute(cur); one barrier/tile.
// K lds [64 keys][128 d], V^T lds [128 d][64 keys], both XOR-swizzled (rule #21).
// No T-split: each wave owns 16 q-rows to completion (no merge pass).
__global__ __launch_bounds__(256) void k_attn(const bf16_t* __restrict__ Q, const bf16_t* __restrict__ Kc,
                                              const bf16_t* __restrict__ VT, bf16_t* __restrict__ O) {
  __shared__ __attribute__((aligned(16))) bf16_t Klds[2][64 * 128];
  __shared__ __attribute__((aligned(16))) bf16_t Vlds[2][128 * 64];
  __shared__ __attribute__((aligned(16))) bf16_t Plds[4][16][72];
  int tid = threadIdx.x;
  int w = tid >> 6, lane = tid & 63, g = lane >> 4, r = lane & 15;
  int h = blockIdx.y, kv = h >> 3;
  int m0 = blockIdx.x * 64;
  int qr0 = m0 + w * 16;
  const bf16_t* qb = Q + ((size_t)h * S_ + qr0 + r) * HD_ + g * 8;
  bx8 qf[4];
  #pragma unroll
  for (int kc = 0; kc < 4; kc++) qf[kc] = *(const bx8*)(qb + kc * 32);
  fx4 of[8] = {};
  float mrun[4], lrun[4];
  #pragma unroll
  for (int i = 0; i < 4; i++) { mrun[i] = -1e30f; lrun[i] = 0.0f; }
  int lim = P_ + qr0 + 4 * g;
  int ntile = (P_ + m0 + 64) >> 6;              // 64-key tiles (block-level causal bound)
  const char* kg = (const char*)(Kc + (size_t)kv * T_ * HD_);   // row=key, stride 256B
  const char* vg = (const char*)(VT + (size_t)kv * HD_ * T_);   // row=d,   stride 4096B
  int wbase = (tid & ~63) * 16;

  auto STAGE = [&](int buf, int t0) {
    #pragma unroll
    for (int j = 0; j < 4; j++) {               // K: 64 rows x 256B = 16KB
      int D = j * 4096 + tid * 16;
      int row = D >> 8, inrow = D & 255;
      const char* src = kg + (size_t)(t0 + row) * 256 + (inrow ^ ((row & 7) << 4));
      GLL16(src, (char*)&Klds[buf][0] + j * 4096 + wbase);
    }
    #pragma unroll
    for (int j = 0; j < 4; j++) {               // V^T: 128 rows x 128B = 16KB
      int D = j * 4096 + tid * 16;
      int row = D >> 7, inrow = D & 127;
      const char* src = vg + (size_t)row * 4096 + (size_t)t0 * 2 + (inrow ^ ((row & 7) << 4));
      GLL16(src, (char*)&Vlds[buf][0] + j * 4096 + wbase);
    }
  };

  STAGE(0, 0);
  __syncthreads();
  int cur = 0;
  for (int t = 0; t < ntile; t++) {
    int t0 = t * 64;
    if (t + 1 < ntile) STAGE(cur ^ 1, t0 + 64);   // issue next tile FIRST
    // ---- QK^T: 16 ds_read + 16 MFMA ----
    const char* kb = (const char*)&Klds[cur][0];
    fx4 sc[4] = {};
    #pragma unroll
    for (int nt = 0; nt < 4; nt++) {
      int row = nt * 16 + r;
      const char* kr = kb + row * 256;
      int sz = (row & 7) << 4;
      #pragma unroll
      for (int kc = 0; kc < 4; kc++)
        sc[nt] = mfma16(qf[kc], *(const bx8*)(kr + (((kc * 32 + g * 8) * 2) ^ sz)), sc[nt]);
    }
    // ---- softmax over 64 keys (defer-max) ----
    float lm[4] = {-1e30f, -1e30f, -1e30f, -1e30f};
    #pragma unroll
    for (int nt = 0; nt < 4; nt++)
      #pragma unroll
      for (int rr = 0; rr < 4; rr++) {
        int key = t0 + nt * 16 + r;
        float sv = sc[nt][rr] * SCALE_;
        sv = (key > lim + rr) ? -1e30f : sv;
        sc[nt][rr] = sv;
        lm[rr] = fmaxf(lm[rr], sv);
      }
    int ok = (lm[0] <= mrun[0] + DEFER_THR_) & (lm[1] <= mrun[1] + DEFER_THR_) &
             (lm[2] <= mrun[2] + DEFER_THR_) & (lm[3] <= mrun[3] + DEFER_THR_);
    if (!__all(ok)) {
      float av[4];
      #pragma unroll
      for (int off = 1; off < 16; off <<= 1)
        #pragma unroll
        for (int rr = 0; rr < 4; rr++) lm[rr] = fmaxf(lm[rr], __shfl_xor(lm[rr], off));
      #pragma unroll
      for (int rr = 0; rr < 4; rr++) {
        float mn = fmaxf(mrun[rr], lm[rr]);
        av[rr] = __expf(mrun[rr] - mn);
        mrun[rr] = mn;
        lrun[rr] *= av[rr];
      }
      #pragma unroll
      for (int f = 0; f < 8; f++)
        #pragma unroll
        for (int rr = 0; rr < 4; rr++) of[f][rr] *= av[rr];
    }
    #pragma unroll
    for (int nt = 0; nt < 4; nt++)
      #pragma unroll
      for (int rr = 0; rr < 4; rr++) {
        float pr = __expf(sc[nt][rr] - mrun[rr]);
        lrun[rr] += pr;
        Plds[w][4 * g + rr][nt * 16 + r] = (bf16_t)pr;
      }
    asm volatile("s_waitcnt lgkmcnt(0)" ::: "memory");  // wave-local LDS RAW fence
    __builtin_amdgcn_sched_barrier(0);
    // ---- PV: 16 ds_read (V^T) + 2 P-frag reads + 16 MFMA ----
    const char* vb = (const char*)&Vlds[cur][0];
    #pragma unroll
    for (int ks = 0; ks < 2; ks++) {
      bx8 pa = *(const bx8*)&Plds[w][r][ks * 32 + g * 8];
      #pragma unroll
      for (int dt = 0; dt < 8; dt++) {
        int row = dt * 16 + r;
        of[dt] = mfma16(pa, *(const bx8*)(vb + row * 128 + (((ks * 32 + g * 8) * 2) ^ ((row & 7) << 4))), of[dt]);
      }
    }
    __syncthreads();   // all waves done with buf cur; next-tile staging drained
    cur ^= 1;
  }
  // final l: reduce per-lane partials across the 16 key-lanes
  #pragma unroll
  for (int off = 1; off < 16; off <<= 1)
    #pragma unroll
    for (int rr = 0; rr < 4; rr++) lrun[rr] += __shfl_xor(lrun[rr], off);
  float li[4];
  #pragma unroll
  for (int rr = 0; rr < 4; rr++) li[rr] = 1.0f / lrun[rr];
  #pragma unroll
  for (int dt = 0; dt < 8; dt++)
    #pragma unroll
    for (int rr = 0; rr < 4; rr++)
      O[(size_t)(qr0 + 4 * g + rr) * H_ + h * HD_ + dt * 16 + r] = (bf16_t)(of[dt][rr] * li[rr]);
}

// ---------------- silu(gate)*up ----------------
__global__ void k_silu_mul(const bf16_t* __restrict__ gb, const bf16_t* __restrict__ ub,
                           bf16_t* __restrict__ ob, int n8) {
  int i = blockIdx.x * 256 + threadIdx.x;
  if (i >= n8) return;
  bx8 gv = ((const bx8*)gb)[i], uv = ((const bx8*)ub)[i];
  bx8 ov;
  #pragma unroll
  for (int j = 0; j < 8; j++) {
    float x = (float)gv[j], y = (float)uv[j];
    float s = x / (1.0f + __expf(-x));
    ov[j] = (bf16_t)(s * y);
  }
  ((bx8*)ob)[i] = ov;
}

// ---------------- host-side launch ----------------
extern "C" void kernel_launch(void* const* d_in, const int* in_sizes, int n_in,
                              void* d_out, int out_size, void* d_ws, size_t ws_size,
                              hipStream_t stream) {
  const float* embeds = (const float*)d_in[0];
  const int*   pos    = (const int*)d_in[1];
  const float* past_k = (const float*)d_in[2];
  const float* past_v = (const float*)d_in[3];
  const float* ln1    = (const float*)d_in[4];
  const float* wq     = (const float*)d_in[5];
  const float* bq     = (const float*)d_in[6];
  const float* wk     = (const float*)d_in[7];
  const float* bk     = (const float*)d_in[8];
  const float* wv     = (const float*)d_in[9];
  const float* bv     = (const float*)d_in[10];
  const float* wo     = (const float*)d_in[11];
  const float* ln2    = (const float*)d_in[12];
  const float* wg     = (const float*)d_in[13];
  const float* wu     = (const float*)d_in[14];
  const float* wd     = (const float*)d_in[15];
  const float* normw  = (const float*)d_in[16];

  char* wsp = (char*)d_ws;
  auto take = [&](size_t n) { char* p = wsp; wsp += (n + 255) & ~(size_t)255; return (void*)p; };
  float*  cos_t  = (float*)take((size_t)S_ * 64 * 4);
  float*  sin_t  = (float*)take((size_t)S_ * 64 * 4);
  float*  cbias  = (float*)take((size_t)L_ * QKVN_ * 4);
  float*  hidden = (float*)take((size_t)S_ * H_ * 4);
  bf16_t* hnorm  = (bf16_t*)take((size_t)S_ * H_ * 2);
  bf16_t* qkv    = (bf16_t*)take((size_t)S_ * QKVN_ * 2);
  bf16_t* qrope  = (bf16_t*)take((size_t)NH_ * S_ * HD_ * 2);
  bf16_t* kcache = (bf16_t*)take((size_t)NKV_ * T_ * HD_ * 2);
  bf16_t* vtr    = (bf16_t*)take((size_t)NKV_ * HD_ * T_ * 2);
  bf16_t* attno  = (bf16_t*)take((size_t)S_ * H_ * 2);
  bf16_t* gateb  = (bf16_t*)take((size_t)S_ * FF_ * 2);
  bf16_t* upb    = (bf16_t*)take((size_t)S_ * FF_ * 2);
  bf16_t* hgb    = (bf16_t*)take((size_t)S_ * FF_ * 2);
  bf16_t* wT     = (bf16_t*)take((size_t)FF_ * H_ * 2);   // max: 5632x2048 bf16

  float* out_h = (float*)d_out;

  k_rope_tables<<<256, 256, 0, stream>>>(pos, cos_t, sin_t);
  k_cbias<<<(L_ * QKVN_ + 255) / 256, 256, 0, stream>>>(bq, bk, bv, cbias);
  k_copy4<<<(S_ * H_ / 4 + 255) / 256, 256, 0, stream>>>(embeds, hidden, S_ * H_ / 4);

  for (int l = 0; l < L_; l++) {
    const float* wq_l = wq + (size_t)l * H_ * (NH_ * HD_);
    const float* wk_l = wk + (size_t)l * H_ * (NKV_ * HD_);
    const float* wv_l = wv + (size_t)l * H_ * (NKV_ * HD_);
    const float* wo_l = wo + (size_t)l * (NH_ * HD_) * H_;
    const float* wg_l = wg + (size_t)l * H_ * FF_;
    const float* wu_l = wu + (size_t)l * H_ * FF_;
    const float* wd_l = wd + (size_t)l * FF_ * H_;
    const float* pk_in = past_k + (size_t)l * NKV_ * P_ * HD_;
    const float* pv_in = past_v + (size_t)l * NKV_ * P_ * HD_;
    float* pk_out = out_h + (size_t)S_ * H_ + (size_t)l * 2 * NKV_ * T_ * HD_;
    float* pv_out = pk_out + (size_t)NKV_ * T_ * HD_;

    // attn input norm
    k_rmsnorm<1><<<S_, 256, 0, stream>>>(hidden, ln1 + (size_t)l * H_, hnorm);
    // fused QKV projection: Bt = [wq^T | wk^T | wv^T] as [2560][2048]
    k_transpose_w<<<dim3(32, 32), 256, 0, stream>>>(wq_l, wT, H_, NH_ * HD_);
    k_transpose_w<<<dim3(4, 32), 256, 0, stream>>>(wk_l, wT + (size_t)KOFF_ * H_, H_, NKV_ * HD_);
    k_transpose_w<<<dim3(4, 32), 256, 0, stream>>>(wv_l, wT + (size_t)VOFF_ * H_, H_, NKV_ * HD_);
    k_gemm<1, 1, 0><<<dim3(QKVN_ / 128, S_ / 64), 256, 0, stream>>>(
        hnorm, wT, cbias + (size_t)l * QKVN_, nullptr, qkv, S_, QKVN_, H_);
    // rope + cache build (also writes f32 present outputs)
    k_rope_q<<<(S_ * NH_ * 64) / 256, 256, 0, stream>>>(qkv, cos_t, sin_t, qrope);
    k_build_k<<<(NKV_ * T_ * 64) / 256, 256, 0, stream>>>(qkv, pk_in, cos_t, sin_t, kcache, pk_out);
    k_build_vt<<<dim3(T_ / 64, HD_ / 64, NKV_), 256, 0, stream>>>(qkv, pv_in, vtr, pv_out);
    // attention (64 q-rows per block, LDS-staged K/V)
    k_attn<<<dim3(S_ / 64, NH_), 256, 0, stream>>>(qrope, kcache, vtr, attno);
    // output projection + residual
    k_transpose_w<<<dim3(32, 32), 256, 0, stream>>>(wo_l, wT, NH_ * HD_, H_);
    k_gemm<0, 0, 1><<<dim3(H_ / 128, S_ / 64), 256, 0, stream>>>(
        attno, wT, nullptr, hidden, hidden, S_, H_, NH_ * HD_);
    // MLP
    k_rmsnorm<1><<<S_, 256, 0, stream>>>(hidden, ln2 + (size_t)l * H_, hnorm);
    k_transpose_w<<<dim3(88, 32), 256, 0, stream>>>(wg_l, wT, H_, FF_);
    k_gemm<1, 0, 0><<<dim3(FF_ / 128, S_ / 64), 256, 0, stream>>>(
        hnorm, wT, nullptr, nullptr, gateb, S_, FF_, H_);
    k_transpose_w<<<dim3(88, 32), 256, 0, stream>>>(wu_l, wT, H_, FF_);
    k_gemm<1, 0, 0><<<dim3(FF_ / 128, S_ / 64), 256, 0, stream>>>(
        hnorm, wT, nullptr, nullptr, upb, S_, FF_, H_);
    k_silu_mul<<<(S_ * FF_ / 8) / 256, 256, 0, stream>>>(gateb, upb, hgb, S_ * FF_ / 8);
    k_transpose_w<<<dim3(32, 88), 256, 0, stream>>>(wd_l, wT, FF_, H_);
    k_gemm<0, 0, 1><<<dim3(H_ / 128, S_ / 64), 256, 0, stream>>>(
        hgb, wT, nullptr, hidden, hidden, S_, H_, FF_);
  }
  k_rmsnorm<0><<<S_, 256, 0, stream>>>(hidden, normw, out_h);
}

// Round 7
// 687.813 us; speedup vs baseline: 1.2918x; 1.0261x over previous
//
#include <hip/hip_runtime.h>

#define L_ 2
#define H_ 2048
#define NH_ 16
#define NKV_ 2
#define HD_ 128
#define S_ 1024
#define P_ 1024
#define T_ 2048
#define FF_ 5632
#define QKVN_ 2560   // NH*HD + 2*NKV*HD
#define KOFF_ 2048
#define VOFF_ 2304

#define EPS_ 1e-6f
#define SCALE_ 0.08838834764831845f   // 1/sqrt(128)
#define DEFER_THR_ 8.0f

typedef __bf16 bf16_t;
typedef __bf16 bx8 __attribute__((ext_vector_type(8)));
typedef __bf16 bx4 __attribute__((ext_vector_type(4)));
typedef float  fx4 __attribute__((ext_vector_type(4)));

__device__ __forceinline__ fx4 mfma16(bx8 a, bx8 b, fx4 c) {
  return __builtin_amdgcn_mfma_f32_16x16x32_bf16(a, b, c, 0, 0, 0);
}

// global->LDS direct, 16B per lane; lds dest = wave-uniform base + lane*16
#define GLL16(gsrc, ldst) __builtin_amdgcn_global_load_lds( \
    (__attribute__((address_space(1))) void*)(gsrc),        \
    (__attribute__((address_space(3))) void*)(ldst), 16, 0, 0)

// ---------------- RoPE tables ----------------
__global__ void k_rope_tables(const int* __restrict__ pos, float* __restrict__ ct, float* __restrict__ st) {
  int i = blockIdx.x * 256 + threadIdx.x;
  if (i >= S_ * 64) return;
  int s = i >> 6, d = i & 63;
  float p = (float)pos[s];
  float inv = expf(-(float)(2 * d) * (13.815510557964274f / 128.0f));  // theta=1e6
  float f = p * inv;
  ct[i] = cosf(f);
  st[i] = sinf(f);
}

__global__ void k_copy4(const float* __restrict__ in, float* __restrict__ out, int n4) {
  int i = blockIdx.x * 256 + threadIdx.x;
  if (i < n4) ((fx4*)out)[i] = ((const fx4*)in)[i];
}

// concat bias: [L][2560] = bq | bk | bv
__global__ void k_cbias(const float* __restrict__ bq, const float* __restrict__ bk,
                        const float* __restrict__ bv, float* __restrict__ cb) {
  int i = blockIdx.x * 256 + threadIdx.x;
  if (i >= L_ * QKVN_) return;
  int l = i / QKVN_, j = i % QKVN_;
  float v;
  if (j < KOFF_)      v = bq[l * KOFF_ + j];
  else if (j < VOFF_) v = bk[l * (NKV_ * HD_) + j - KOFF_];
  else                v = bv[l * (NKV_ * HD_) + j - VOFF_];
  cb[i] = v;
}

// ---------------- RMSNorm (one block per row) ----------------
template<int OUTBF>
__global__ __launch_bounds__(256) void k_rmsnorm(const float* __restrict__ x, const float* __restrict__ w,
                                                 void* __restrict__ y) {
  int row = blockIdx.x, tid = threadIdx.x;
  const fx4* xr = (const fx4*)(x + (size_t)row * H_);
  fx4 v0 = xr[tid], v1 = xr[tid + 256];
  float ss = v0[0]*v0[0] + v0[1]*v0[1] + v0[2]*v0[2] + v0[3]*v0[3]
           + v1[0]*v1[0] + v1[1]*v1[1] + v1[2]*v1[2] + v1[3]*v1[3];
  #pragma unroll
  for (int off = 32; off > 0; off >>= 1) ss += __shfl_xor(ss, off);
  __shared__ float red[4];
  if ((tid & 63) == 0) red[tid >> 6] = ss;
  __syncthreads();
  float tot = red[0] + red[1] + red[2] + red[3];
  float rs = rsqrtf(tot * (1.0f / H_) + EPS_);
  const fx4* wr_ = (const fx4*)w;
  fx4 w0 = wr_[tid], w1 = wr_[tid + 256];
  if (OUTBF) {
    bf16_t* yb = (bf16_t*)y + (size_t)row * H_;
    bx4 o0, o1;
    #pragma unroll
    for (int i = 0; i < 4; i++) { o0[i] = (bf16_t)(v0[i] * rs * w0[i]); o1[i] = (bf16_t)(v1[i] * rs * w1[i]); }
    *(bx4*)&yb[tid * 4] = o0;
    *(bx4*)&yb[(tid + 256) * 4] = o1;
  } else {
    float* yf = (float*)y + (size_t)row * H_;
    fx4 o0, o1;
    #pragma unroll
    for (int i = 0; i < 4; i++) { o0[i] = v0[i] * rs * w0[i]; o1[i] = v1[i] * rs * w1[i]; }
    *(fx4*)&yf[tid * 4] = o0;
    *(fx4*)&yf[(tid + 256) * 4] = o1;
  }
}

// ---------------- weight transpose+convert: out[C][R] = bf16(in[R][C]^T) ----------------
__global__ __launch_bounds__(256) void k_transpose_w(const float* __restrict__ in, bf16_t* __restrict__ out,
                                                     int R, int C) {
  __shared__ __attribute__((aligned(16))) float Tt[64 * 68];
  int tid = threadIdx.x;
  int c0 = blockIdx.x * 64, r0 = blockIdx.y * 64;
  #pragma unroll
  for (int j = 0; j < 4; j++) {
    int c = j * 256 + tid;
    int row = c >> 4, col = (c & 15) * 4;
    *(fx4*)&Tt[row * 68 + col] = *(const fx4*)&in[(size_t)(r0 + row) * C + c0 + col];
  }
  __syncthreads();
  #pragma unroll
  for (int j = 0; j < 2; j++) {
    int c = j * 256 + tid;
    int n = c >> 3, ko = (c & 7) * 8;
    bx8 o;
    #pragma unroll
    for (int i = 0; i < 8; i++) o[i] = (bf16_t)Tt[(ko + i) * 68 + n];
    *(bx8*)&out[(size_t)(c0 + n) * R + r0 + ko] = o;
  }
}

// ---------------- GEMM: C[M,N] = A[M,K](bf16) * Bt[N,K]^T (bf16) ----------------
// BM=64 BN=128 BK=64, 2-phase double-buffered LDS: STAGE(next) issued before
// compute(cur), ONE barrier per K-step — load latency overlaps ds_read+MFMA.
template<int OUTBF, int HASB, int HASR>
__global__ __launch_bounds__(256) void k_gemm(const bf16_t* __restrict__ A, const bf16_t* __restrict__ Bt,
                                              const float* __restrict__ bias, const float* __restrict__ res,
                                              void* __restrict__ out, int M, int N, int K) {
  __shared__ __attribute__((aligned(16))) bf16_t sA[2][64 * 64];
  __shared__ __attribute__((aligned(16))) bf16_t sB[2][128 * 64];
  int tid = threadIdx.x;
  int w = tid >> 6, lane = tid & 63, g = lane >> 4, r = lane & 15;
  int wr = w >> 1, wc = w & 1;
  int m0 = blockIdx.y * 64;
  int n0 = blockIdx.x * 128;
  fx4 acc[2][4] = {};
  int swz = (r & 7) << 4;
  int col0 = (g * 16) ^ swz;
  int col1 = (64 + g * 16) ^ swz;
  int wbase = (tid & ~63) * 16;
  int nk = K >> 6;

  auto STAGE = [&](int buf, int k0) {
    #pragma unroll
    for (int j = 0; j < 2; j++) {
      int d = (j * 256 + tid) * 16;
      int row = d >> 7;
      int inrow = (d & 127) ^ ((row & 7) << 4);
      GLL16((const char*)(A + (size_t)(m0 + row) * K + k0) + inrow,
            (char*)&sA[buf][0] + j * 4096 + wbase);
    }
    #pragma unroll
    for (int j = 0; j < 4; j++) {
      int d = (j * 256 + tid) * 16;
      int row = d >> 7;
      int inrow = (d & 127) ^ ((row & 7) << 4);
      GLL16((const char*)(Bt + (size_t)(n0 + row) * K + k0) + inrow,
            (char*)&sB[buf][0] + j * 4096 + wbase);
    }
  };

  STAGE(0, 0);
  __syncthreads();
  int cur = 0;
  for (int t = 0; t < nk; t++) {
    if (t + 1 < nk) STAGE(cur ^ 1, (t + 1) << 6);   // issue next tile FIRST
    const char* pa = (const char*)&sA[cur][0] + (wr * 32 + r) * 128;
    const char* pb = (const char*)&sB[cur][0] + (wc * 64 + r) * 128;
    bx8 fa[2][2], fb[4][2];
    #pragma unroll
    for (int m = 0; m < 2; m++) {
      fa[m][0] = *(const bx8*)(pa + m * 2048 + col0);
      fa[m][1] = *(const bx8*)(pa + m * 2048 + col1);
    }
    #pragma unroll
    for (int n = 0; n < 4; n++) {
      fb[n][0] = *(const bx8*)(pb + n * 2048 + col0);
      fb[n][1] = *(const bx8*)(pb + n * 2048 + col1);
    }
    #pragma unroll
    for (int kk = 0; kk < 2; kk++)
      #pragma unroll
      for (int n = 0; n < 4; n++) {
        acc[0][n] = mfma16(fa[0][kk], fb[n][kk], acc[0][n]);
        acc[1][n] = mfma16(fa[1][kk], fb[n][kk], acc[1][n]);
      }
    __syncthreads();   // drains staged loads (overlapped w/ compute) + guards buf reuse
    cur ^= 1;
  }
  #pragma unroll
  for (int m = 0; m < 2; m++)
    #pragma unroll
    for (int n = 0; n < 4; n++) {
      int col = n0 + wc * 64 + n * 16 + r;
      #pragma unroll
      for (int rr = 0; rr < 4; rr++) {
        int row = m0 + wr * 32 + m * 16 + 4 * g + rr;
        float v = acc[m][n][rr];
        if (HASB) v += bias[col];
        if (HASR) v += res[(size_t)row * N + col];
        if (OUTBF) ((bf16_t*)out)[(size_t)row * N + col] = (bf16_t)v;
        else       ((float*)out)[(size_t)row * N + col] = v;
      }
    }
}

// ---------------- RoPE on Q: qkv[S][2560] bf16 -> [NH][S][HD] bf16 ----------------
__global__ void k_rope_q(const bf16_t* __restrict__ qkv, const float* __restrict__ ct,
                         const float* __restrict__ st, bf16_t* __restrict__ qout) {
  int i = blockIdx.x * 256 + threadIdx.x;
  if (i >= S_ * NH_ * 64) return;
  int d = i & 63, h = (i >> 6) & 15, s = i >> 10;
  size_t ib = (size_t)s * QKVN_ + h * HD_;
  float x1 = (float)qkv[ib + d];
  float x2 = (float)qkv[ib + d + 64];
  float c = ct[s * 64 + d], sn = st[s * 64 + d];
  size_t ob = ((size_t)h * S_ + s) * HD_;
  qout[ob + d]      = (bf16_t)(x1 * c - x2 * sn);
  qout[ob + d + 64] = (bf16_t)(x2 * c + x1 * sn);
}

// ---------------- K: rope new keys + concat past -> bf16 [NKV][T][HD] + f32 present ----------------
__global__ void k_build_k(const bf16_t* __restrict__ qkv, const float* __restrict__ pastk,
                          const float* __restrict__ ct, const float* __restrict__ st,
                          bf16_t* __restrict__ kc, float* __restrict__ pk_out) {
  int i = blockIdx.x * 256 + threadIdx.x;
  if (i >= NKV_ * T_ * 64) return;
  int d = i & 63, t = (i >> 6) & (T_ - 1), kv = i >> 17;
  size_t cb = ((size_t)kv * T_ + t) * HD_;
  if (t < P_) {
    size_t pb = ((size_t)kv * P_ + t) * HD_;
    float a = pastk[pb + d], b = pastk[pb + d + 64];
    kc[cb + d] = (bf16_t)a; kc[cb + d + 64] = (bf16_t)b;
    pk_out[cb + d] = a;     pk_out[cb + d + 64] = b;
  } else {
    int s = t - P_;
    size_t ib = (size_t)s * QKVN_ + KOFF_ + kv * HD_;
    float x1 = (float)qkv[ib + d];
    float x2 = (float)qkv[ib + d + 64];
    float c = ct[s * 64 + d], sn = st[s * 64 + d];
    float k1 = x1 * c - x2 * sn, k2 = x2 * c + x1 * sn;
    kc[cb + d] = (bf16_t)k1; kc[cb + d + 64] = (bf16_t)k2;
    pk_out[cb + d] = k1;     pk_out[cb + d + 64] = k2;
  }
}

// ---------------- V: concat past+new -> VT bf16 [NKV][HD][T] + f32 present ----------------
__global__ __launch_bounds__(256) void k_build_vt(const bf16_t* __restrict__ qkv, const float* __restrict__ pastv,
                                                  bf16_t* __restrict__ vt, float* __restrict__ pv_out) {
  int t0 = blockIdx.x * 64, d0 = blockIdx.y * 64, kv = blockIdx.z;
  __shared__ __attribute__((aligned(16))) float Tt[64 * 68];
  int tid = threadIdx.x;
  if (t0 < P_) {
    #pragma unroll
    for (int j = 0; j < 4; j++) {
      int c = j * 256 + tid;
      int row = c >> 4, col = (c & 15) * 4;
      int t = t0 + row;
      fx4 v = *(const fx4*)&pastv[((size_t)kv * P_ + t) * HD_ + d0 + col];
      *(fx4*)&Tt[row * 68 + col] = v;
      *(fx4*)&pv_out[((size_t)kv * T_ + t) * HD_ + d0 + col] = v;
    }
  } else {
    #pragma unroll
    for (int j = 0; j < 4; j++) {
      int c = j * 256 + tid;
      int row = c >> 4, col = (c & 15) * 4;
      int t = t0 + row;
      bx4 b = *(const bx4*)&qkv[(size_t)(t - P_) * QKVN_ + VOFF_ + kv * HD_ + d0 + col];
      fx4 v;
      #pragma unroll
      for (int q = 0; q < 4; q++) v[q] = (float)b[q];
      *(fx4*)&Tt[row * 68 + col] = v;
      *(fx4*)&pv_out[((size_t)kv * T_ + t) * HD_ + d0 + col] = v;
    }
  }
  __syncthreads();
  #pragma unroll
  for (int j = 0; j < 2; j++) {
    int c = j * 256 + tid;
    int n = c >> 3, ko = (c & 7) * 8;
    bx8 o;
    #pragma unroll
    for (int i = 0; i < 8; i++) o[i] = (bf16_t)Tt[(ko + i) * 68 + n];
    *(bx8*)&vt[((size_t)kv * HD_ + d0 + n) * T_ + t0 + ko] = o;
  }
}

// ---------------- flash attention v5: block = 64 q-rows, LDS-staged K/V tiles ----------------
__global__ __launch_bounds__(256) void k_attn(const bf16_t* __restrict__ Q, const bf16_t* __restrict__ Kc,
                                              const bf16_t* __restrict__ VT, bf16_t* __restrict__ O) {
  __shared__ __attribute__((aligned(16))) bf16_t Klds[2][64 * 128];
  __shared__ __attribute__((aligned(16))) bf16_t Vlds[2][128 * 64];
  __shared__ __attribute__((aligned(16))) bf16_t Plds[4][16][72];
  int tid = threadIdx.x;
  int w = tid >> 6, lane = tid & 63, g = lane >> 4, r = lane & 15;
  int h = blockIdx.y, kv = h >> 3;
  int m0 = blockIdx.x * 64;
  int qr0 = m0 + w * 16;
  const bf16_t* qb = Q + ((size_t)h * S_ + qr0 + r) * HD_ + g * 8;
  bx8 qf[4];
  #pragma unroll
  for (int kc = 0; kc < 4; kc++) qf[kc] = *(const bx8*)(qb + kc * 32);
  fx4 of[8] = {};
  float mrun[4], lrun[4];
  #pragma unroll
  for (int i = 0; i < 4; i++) { mrun[i] = -1e30f; lrun[i] = 0.0f; }
  int lim = P_ + qr0 + 4 * g;
  int ntile = (P_ + m0 + 64) >> 6;
  const char* kg = (const char*)(Kc + (size_t)kv * T_ * HD_);
  const char* vg = (const char*)(VT + (size_t)kv * HD_ * T_);
  int wbase = (tid & ~63) * 16;

  auto STAGE = [&](int buf, int t0) {
    #pragma unroll
    for (int j = 0; j < 4; j++) {
      int D = j * 4096 + tid * 16;
      int row = D >> 8, inrow = D & 255;
      const char* src = kg + (size_t)(t0 + row) * 256 + (inrow ^ ((row & 7) << 4));
      GLL16(src, (char*)&Klds[buf][0] + j * 4096 + wbase);
    }
    #pragma unroll
    for (int j = 0; j < 4; j++) {
      int D = j * 4096 + tid * 16;
      int row = D >> 7, inrow = D & 127;
      const char* src = vg + (size_t)row * 4096 + (size_t)t0 * 2 + (inrow ^ ((row & 7) << 4));
      GLL16(src, (char*)&Vlds[buf][0] + j * 4096 + wbase);
    }
  };

  STAGE(0, 0);
  __syncthreads();
  int cur = 0;
  for (int t = 0; t < ntile; t++) {
    int t0 = t * 64;
    if (t + 1 < ntile) STAGE(cur ^ 1, t0 + 64);
    const char* kb = (const char*)&Klds[cur][0];
    fx4 sc[4] = {};
    #pragma unroll
    for (int nt = 0; nt < 4; nt++) {
      int row = nt * 16 + r;
      const char* kr = kb + row * 256;
      int sz = (row & 7) << 4;
      #pragma unroll
      for (int kc = 0; kc < 4; kc++)
        sc[nt] = mfma16(qf[kc], *(const bx8*)(kr + (((kc * 32 + g * 8) * 2) ^ sz)), sc[nt]);
    }
    float lm[4] = {-1e30f, -1e30f, -1e30f, -1e30f};
    #pragma unroll
    for (int nt = 0; nt < 4; nt++)
      #pragma unroll
      for (int rr = 0; rr < 4; rr++) {
        int key = t0 + nt * 16 + r;
        float sv = sc[nt][rr] * SCALE_;
        sv = (key > lim + rr) ? -1e30f : sv;
        sc[nt][rr] = sv;
        lm[rr] = fmaxf(lm[rr], sv);
      }
    int ok = (lm[0] <= mrun[0] + DEFER_THR_) & (lm[1] <= mrun[1] + DEFER_THR_) &
             (lm[2] <= mrun[2] + DEFER_THR_) & (lm[3] <= mrun[3] + DEFER_THR_);
    if (!__all(ok)) {
      float av[4];
      #pragma unroll
      for (int off = 1; off < 16; off <<= 1)
        #pragma unroll
        for (int rr = 0; rr < 4; rr++) lm[rr] = fmaxf(lm[rr], __shfl_xor(lm[rr], off));
      #pragma unroll
      for (int rr = 0; rr < 4; rr++) {
        float mn = fmaxf(mrun[rr], lm[rr]);
        av[rr] = __expf(mrun[rr] - mn);
        mrun[rr] = mn;
        lrun[rr] *= av[rr];
      }
      #pragma unroll
      for (int f = 0; f < 8; f++)
        #pragma unroll
        for (int rr = 0; rr < 4; rr++) of[f][rr] *= av[rr];
    }
    #pragma unroll
    for (int nt = 0; nt < 4; nt++)
      #pragma unroll
      for (int rr = 0; rr < 4; rr++) {
        float pr = __expf(sc[nt][rr] - mrun[rr]);
        lrun[rr] += pr;
        Plds[w][4 * g + rr][nt * 16 + r] = (bf16_t)pr;
      }
    asm volatile("s_waitcnt lgkmcnt(0)" ::: "memory");
    __builtin_amdgcn_sched_barrier(0);
    const char* vb = (const char*)&Vlds[cur][0];
    #pragma unroll
    for (int ks = 0; ks < 2; ks++) {
      bx8 pa = *(const bx8*)&Plds[w][r][ks * 32 + g * 8];
      #pragma unroll
      for (int dt = 0; dt < 8; dt++) {
        int row = dt * 16 + r;
        of[dt] = mfma16(pa, *(const bx8*)(vb + row * 128 + (((ks * 32 + g * 8) * 2) ^ ((row & 7) << 4))), of[dt]);
      }
    }
    __syncthreads();
    cur ^= 1;
  }
  #pragma unroll
  for (int off = 1; off < 16; off <<= 1)
    #pragma unroll
    for (int rr = 0; rr < 4; rr++) lrun[rr] += __shfl_xor(lrun[rr], off);
  float li[4];
  #pragma unroll
  for (int rr = 0; rr < 4; rr++) li[rr] = 1.0f / lrun[rr];
  #pragma unroll
  for (int dt = 0; dt < 8; dt++)
    #pragma unroll
    for (int rr = 0; rr < 4; rr++)
      O[(size_t)(qr0 + 4 * g + rr) * H_ + h * HD_ + dt * 16 + r] = (bf16_t)(of[dt][rr] * li[rr]);
}

// ---------------- silu(gate)*up ----------------
__global__ void k_silu_mul(const bf16_t* __restrict__ gb, const bf16_t* __restrict__ ub,
                           bf16_t* __restrict__ ob, int n8) {
  int i = blockIdx.x * 256 + threadIdx.x;
  if (i >= n8) return;
  bx8 gv = ((const bx8*)gb)[i], uv = ((const bx8*)ub)[i];
  bx8 ov;
  #pragma unroll
  for (int j = 0; j < 8; j++) {
    float x = (float)gv[j], y = (float)uv[j];
    float s = x / (1.0f + __expf(-x));
    ov[j] = (bf16_t)(s * y);
  }
  ((bx8*)ob)[i] = ov;
}

// ---------------- host-side launch ----------------
extern "C" void kernel_launch(void* const* d_in, const int* in_sizes, int n_in,
                              void* d_out, int out_size, void* d_ws, size_t ws_size,
                              hipStream_t stream) {
  const float* embeds = (const float*)d_in[0];
  const int*   pos    = (const int*)d_in[1];
  const float* past_k = (const float*)d_in[2];
  const float* past_v = (const float*)d_in[3];
  const float* ln1    = (const float*)d_in[4];
  const float* wq     = (const float*)d_in[5];
  const float* bq     = (const float*)d_in[6];
  const float* wk     = (const float*)d_in[7];
  const float* bk     = (const float*)d_in[8];
  const float* wv     = (const float*)d_in[9];
  const float* bv     = (const float*)d_in[10];
  const float* wo     = (const float*)d_in[11];
  const float* ln2    = (const float*)d_in[12];
  const float* wg     = (const float*)d_in[13];
  const float* wu     = (const float*)d_in[14];
  const float* wd     = (const float*)d_in[15];
  const float* normw  = (const float*)d_in[16];

  char* wsp = (char*)d_ws;
  auto take = [&](size_t n) { char* p = wsp; wsp += (n + 255) & ~(size_t)255; return (void*)p; };
  float*  cos_t  = (float*)take((size_t)S_ * 64 * 4);
  float*  sin_t  = (float*)take((size_t)S_ * 64 * 4);
  float*  cbias  = (float*)take((size_t)L_ * QKVN_ * 4);
  float*  hidden = (float*)take((size_t)S_ * H_ * 4);
  bf16_t* hnorm  = (bf16_t*)take((size_t)S_ * H_ * 2);
  bf16_t* qkv    = (bf16_t*)take((size_t)S_ * QKVN_ * 2);
  bf16_t* qrope  = (bf16_t*)take((size_t)NH_ * S_ * HD_ * 2);
  bf16_t* kcache = (bf16_t*)take((size_t)NKV_ * T_ * HD_ * 2);
  bf16_t* vtr    = (bf16_t*)take((size_t)NKV_ * HD_ * T_ * 2);
  bf16_t* attno  = (bf16_t*)take((size_t)S_ * H_ * 2);
  bf16_t* gateb  = (bf16_t*)take((size_t)S_ * FF_ * 2);
  bf16_t* upb    = (bf16_t*)take((size_t)S_ * FF_ * 2);
  bf16_t* hgb    = (bf16_t*)take((size_t)S_ * FF_ * 2);
  bf16_t* wT     = (bf16_t*)take((size_t)FF_ * H_ * 2);   // max: 5632x2048 bf16

  float* out_h = (float*)d_out;

  k_rope_tables<<<256, 256, 0, stream>>>(pos, cos_t, sin_t);
  k_cbias<<<(L_ * QKVN_ + 255) / 256, 256, 0, stream>>>(bq, bk, bv, cbias);
  k_copy4<<<(S_ * H_ / 4 + 255) / 256, 256, 0, stream>>>(embeds, hidden, S_ * H_ / 4);

  for (int l = 0; l < L_; l++) {
    const float* wq_l = wq + (size_t)l * H_ * (NH_ * HD_);
    const float* wk_l = wk + (size_t)l * H_ * (NKV_ * HD_);
    const float* wv_l = wv + (size_t)l * H_ * (NKV_ * HD_);
    const float* wo_l = wo + (size_t)l * (NH_ * HD_) * H_;
    const float* wg_l = wg + (size_t)l * H_ * FF_;
    const float* wu_l = wu + (size_t)l * H_ * FF_;
    const float* wd_l = wd + (size_t)l * FF_ * H_;
    const float* pk_in = past_k + (size_t)l * NKV_ * P_ * HD_;
    const float* pv_in = past_v + (size_t)l * NKV_ * P_ * HD_;
    float* pk_out = out_h + (size_t)S_ * H_ + (size_t)l * 2 * NKV_ * T_ * HD_;
    float* pv_out = pk_out + (size_t)NKV_ * T_ * HD_;

    // attn input norm
    k_rmsnorm<1><<<S_, 256, 0, stream>>>(hidden, ln1 + (size_t)l * H_, hnorm);
    // fused QKV projection: Bt = [wq^T | wk^T | wv^T] as [2560][2048]
    k_transpose_w<<<dim3(32, 32), 256, 0, stream>>>(wq_l, wT, H_, NH_ * HD_);
    k_transpose_w<<<dim3(4, 32), 256, 0, stream>>>(wk_l, wT + (size_t)KOFF_ * H_, H_, NKV_ * HD_);
    k_transpose_w<<<dim3(4, 32), 256, 0, stream>>>(wv_l, wT + (size_t)VOFF_ * H_, H_, NKV_ * HD_);
    k_gemm<1, 1, 0><<<dim3(QKVN_ / 128, S_ / 64), 256, 0, stream>>>(
        hnorm, wT, cbias + (size_t)l * QKVN_, nullptr, qkv, S_, QKVN_, H_);
    // rope + cache build (also writes f32 present outputs)
    k_rope_q<<<(S_ * NH_ * 64) / 256, 256, 0, stream>>>(qkv, cos_t, sin_t, qrope);
    k_build_k<<<(NKV_ * T_ * 64) / 256, 256, 0, stream>>>(qkv, pk_in, cos_t, sin_t, kcache, pk_out);
    k_build_vt<<<dim3(T_ / 64, HD_ / 64, NKV_), 256, 0, stream>>>(qkv, pv_in, vtr, pv_out);
    // attention (64 q-rows per block, LDS-staged K/V)
    k_attn<<<dim3(S_ / 64, NH_), 256, 0, stream>>>(qrope, kcache, vtr, attno);
    // output projection + residual
    k_transpose_w<<<dim3(32, 32), 256, 0, stream>>>(wo_l, wT, NH_ * HD_, H_);
    k_gemm<0, 0, 1><<<dim3(H_ / 128, S_ / 64), 256, 0, stream>>>(
        attno, wT, nullptr, hidden, hidden, S_, H_, NH_ * HD_);
    // MLP
    k_rmsnorm<1><<<S_, 256, 0, stream>>>(hidden, ln2 + (size_t)l * H_, hnorm);
    k_transpose_w<<<dim3(88, 32), 256, 0, stream>>>(wg_l, wT, H_, FF_);
    k_gemm<1, 0, 0><<<dim3(FF_ / 128, S_ / 64), 256, 0, stream>>>(
        hnorm, wT, nullptr, nullptr, gateb, S_, FF_, H_);
    k_transpose_w<<<dim3(88, 32), 256, 0, stream>>>(wu_l, wT, H_, FF_);
    k_gemm<1, 0, 0><<<dim3(FF_ / 128, S_ / 64), 256, 0, stream>>>(
        hnorm, wT, nullptr, nullptr, upb, S_, FF_, H_);
    k_silu_mul<<<(S_ * FF_ / 8) / 256, 256, 0, stream>>>(gateb, upb, hgb, S_ * FF_ / 8);
    k_transpose_w<<<dim3(32, 88), 256, 0, stream>>>(wd_l, wT, FF_, H_);
    k_gemm<0, 0, 1><<<dim3(H_ / 128, S_ / 64), 256, 0, stream>>>(
        hgb, wT, nullptr, hidden, hidden, S_, H_, FF_);
  }
  k_rmsnorm<0><<<S_, 256, 0, stream>>>(hidden, normw, out_h);
}